// Round 1
// baseline (68130.615 us; speedup 1.0000x reference)
//
#include <hip/hip_runtime.h>
#include <hip/hip_bf16.h>
#include <math.h>

#define D 512
#define HID 2048
#define LAYERS 4
#define V 32000
#define BATCH 2
#define T 1025
#define MB 128
#define NH 8
#define DH 64
#define NTOK 256            // BATCH*MB rows per chunk
#define LR 0.0003f
#define NCHUNK 8

// ---------------- reductions ----------------
__device__ __forceinline__ float block_sum(float v, float* sbuf) {
    int t = threadIdx.x;
    for (int o = 32; o > 0; o >>= 1) v += __shfl_down(v, o, 64);
    if ((t & 63) == 0) sbuf[t >> 6] = v;
    __syncthreads();
    int nw = blockDim.x >> 6;
    float r = (t < nw) ? sbuf[t] : 0.f;
    if (t < 64) { for (int o = 32; o > 0; o >>= 1) r += __shfl_down(r, o, 64); }
    if (t == 0) sbuf[0] = r;
    __syncthreads();
    float out = sbuf[0];
    __syncthreads();
    return out;
}

__device__ __forceinline__ float block_max(float v, float* sbuf) {
    int t = threadIdx.x;
    for (int o = 32; o > 0; o >>= 1) v = fmaxf(v, __shfl_down(v, o, 64));
    if ((t & 63) == 0) sbuf[t >> 6] = v;
    __syncthreads();
    int nw = blockDim.x >> 6;
    float r = (t < nw) ? sbuf[t] : -1e30f;
    if (t < 64) { for (int o = 32; o > 0; o >>= 1) r = fmaxf(r, __shfl_down(r, o, 64)); }
    if (t == 0) sbuf[0] = r;
    __syncthreads();
    float out = sbuf[0];
    __syncthreads();
    return out;
}

// ---------------- embedding ----------------
__global__ void embed_kernel(const int* __restrict__ x, const float* __restrict__ emb,
                             const float* __restrict__ pos, float* __restrict__ h0, int c) {
    int n = blockIdx.x;          // 0..255
    int b = n >> 7, i = n & 127;
    int tok = x[b * T + c * MB + i];
    for (int d = threadIdx.x; d < D; d += blockDim.x)
        h0[(size_t)n * D + d] = emb[(size_t)tok * D + d] + pos[(size_t)i * D + d];
}

// ---------------- layernorm fwd ----------------
__global__ void ln_fwd(const float* __restrict__ x, const float* __restrict__ s,
                       const float* __restrict__ bb, float* __restrict__ y) {
    __shared__ float sbuf[8];
    int row = blockIdx.x;
    const float* xr = x + (size_t)row * D;
    float* yr = y + (size_t)row * D;
    float sum = 0;
    for (int d = threadIdx.x; d < D; d += blockDim.x) sum += xr[d];
    float mean = block_sum(sum, sbuf) / D;
    float vs = 0;
    for (int d = threadIdx.x; d < D; d += blockDim.x) { float t = xr[d] - mean; vs += t * t; }
    float var = block_sum(vs, sbuf) / D;
    float rstd = rsqrtf(var + 1e-5f);
    for (int d = threadIdx.x; d < D; d += blockDim.x)
        yr[d] = (xr[d] - mean) * rstd * s[d] + bb[d];
}

// ---------------- layernorm bwd (dx = LNbwd(dy) + addend) ----------------
__global__ void ln_bwd(const float* __restrict__ dy, const float* __restrict__ x,
                       const float* __restrict__ s, const float* __restrict__ addend,
                       float* __restrict__ dx) {
    __shared__ float sbuf[8];
    int row = blockIdx.x;
    const float* xr = x + (size_t)row * D;
    const float* dyr = dy + (size_t)row * D;
    float sum = 0;
    for (int d = threadIdx.x; d < D; d += blockDim.x) sum += xr[d];
    float mean = block_sum(sum, sbuf) / D;
    float vs = 0;
    for (int d = threadIdx.x; d < D; d += blockDim.x) { float t = xr[d] - mean; vs += t * t; }
    float var = block_sum(vs, sbuf) / D;
    float rstd = rsqrtf(var + 1e-5f);
    float d1 = 0, d2 = 0;
    for (int d = threadIdx.x; d < D; d += blockDim.x) {
        float xh = (xr[d] - mean) * rstd;
        float t1 = s[d] * dyr[d];
        d1 += t1; d2 += t1 * xh;
    }
    float dot1 = block_sum(d1, sbuf);
    float dot2 = block_sum(d2, sbuf);
    for (int d = threadIdx.x; d < D; d += blockDim.x) {
        float xh = (xr[d] - mean) * rstd;
        float t1 = s[d] * dyr[d];
        float v = rstd * (t1 - (dot1 + xh * dot2) * (1.f / D));
        if (addend) v += addend[(size_t)row * D + d];
        dx[(size_t)row * D + d] = v;
    }
}

// ---------------- GEMM NN: C = A@B (+bias) (+res) ----------------
__global__ __launch_bounds__(256) void gemm_nn(const float* __restrict__ A, int lda,
        const float* __restrict__ B, int ldb, float* __restrict__ C, int ldc,
        int K, const float* __restrict__ bias, const float* __restrict__ res, int ldres) {
    __shared__ __align__(16) float As[64][20];
    __shared__ __align__(16) float Bs[16][64];
    int t = threadIdx.x, tx = t & 15, ty = t >> 4;
    int m0 = blockIdx.y * 64, n0 = blockIdx.x * 64;
    int lAm = t >> 2, lAk = (t & 3) * 4;
    int lBk = t >> 4, lBn = (t & 15) * 4;
    float acc[4][4] = {};
    for (int k0 = 0; k0 < K; k0 += 16) {
        float4 av = *(const float4*)&A[(size_t)(m0 + lAm) * lda + k0 + lAk];
        float4 bv = *(const float4*)&B[(size_t)(k0 + lBk) * ldb + n0 + lBn];
        *(float4*)&As[lAm][lAk] = av;
        *(float4*)&Bs[lBk][lBn] = bv;
        __syncthreads();
#pragma unroll
        for (int kk = 0; kk < 16; kk++) {
            float a[4], b[4];
#pragma unroll
            for (int i = 0; i < 4; i++) a[i] = As[ty * 4 + i][kk];
#pragma unroll
            for (int j = 0; j < 4; j++) b[j] = Bs[kk][tx * 4 + j];
#pragma unroll
            for (int i = 0; i < 4; i++)
#pragma unroll
                for (int j = 0; j < 4; j++) acc[i][j] += a[i] * b[j];
        }
        __syncthreads();
    }
#pragma unroll
    for (int i = 0; i < 4; i++) {
        int m = m0 + ty * 4 + i;
#pragma unroll
        for (int j = 0; j < 4; j++) {
            int n = n0 + tx * 4 + j;
            float v = acc[i][j];
            if (bias) v += bias[n];
            if (res) v += res[(size_t)m * ldres + n];
            C[(size_t)m * ldc + n] = v;
        }
    }
}

// ---------------- GEMM NT: C[m,n] = sum_k A[m,k]*B[n,k] ----------------
__global__ __launch_bounds__(256) void gemm_nt(const float* __restrict__ A, int lda,
        const float* __restrict__ B, int ldb, float* __restrict__ C, int ldc, int K) {
    __shared__ __align__(16) float As[64][20];
    __shared__ __align__(16) float Bs[64][20];
    int t = threadIdx.x, tx = t & 15, ty = t >> 4;
    int m0 = blockIdx.y * 64, n0 = blockIdx.x * 64;
    int lAm = t >> 2, lAk = (t & 3) * 4;
    float acc[4][4] = {};
    for (int k0 = 0; k0 < K; k0 += 16) {
        float4 av = *(const float4*)&A[(size_t)(m0 + lAm) * lda + k0 + lAk];
        float4 bv = *(const float4*)&B[(size_t)(n0 + lAm) * ldb + k0 + lAk];
        *(float4*)&As[lAm][lAk] = av;
        *(float4*)&Bs[lAm][lAk] = bv;
        __syncthreads();
#pragma unroll
        for (int kk = 0; kk < 16; kk++) {
            float a[4], b[4];
#pragma unroll
            for (int i = 0; i < 4; i++) a[i] = As[ty * 4 + i][kk];
#pragma unroll
            for (int j = 0; j < 4; j++) b[j] = Bs[tx * 4 + j][kk];
#pragma unroll
            for (int i = 0; i < 4; i++)
#pragma unroll
                for (int j = 0; j < 4; j++) acc[i][j] += a[i] * b[j];
        }
        __syncthreads();
    }
#pragma unroll
    for (int i = 0; i < 4; i++) {
        int m = m0 + ty * 4 + i;
#pragma unroll
        for (int j = 0; j < 4; j++)
            C[(size_t)m * ldc + n0 + tx * 4 + j] = acc[i][j];
    }
}

// ---------------- GEMM TN + SGD update: P[m,n] -= lr * sum_k X[k,m]*dY[k,n] ----------------
__global__ __launch_bounds__(256) void gemm_tn_update(const float* __restrict__ X, int ldx,
        const float* __restrict__ dY, int ldy, float* __restrict__ P, int ldp, int K, float lr) {
    __shared__ __align__(16) float Xs[16][64];
    __shared__ __align__(16) float Ys[16][64];
    int t = threadIdx.x, tx = t & 15, ty = t >> 4;
    int m0 = blockIdx.y * 64, n0 = blockIdx.x * 64;
    int lk = t >> 4, lm = (t & 15) * 4;
    float acc[4][4] = {};
    for (int k0 = 0; k0 < K; k0 += 16) {
        float4 xv = *(const float4*)&X[(size_t)(k0 + lk) * ldx + m0 + lm];
        float4 yv = *(const float4*)&dY[(size_t)(k0 + lk) * ldy + n0 + lm];
        *(float4*)&Xs[lk][lm] = xv;
        *(float4*)&Ys[lk][lm] = yv;
        __syncthreads();
#pragma unroll
        for (int kk = 0; kk < 16; kk++) {
            float a[4], b[4];
#pragma unroll
            for (int i = 0; i < 4; i++) a[i] = Xs[kk][ty * 4 + i];
#pragma unroll
            for (int j = 0; j < 4; j++) b[j] = Ys[kk][tx * 4 + j];
#pragma unroll
            for (int i = 0; i < 4; i++)
#pragma unroll
                for (int j = 0; j < 4; j++) acc[i][j] += a[i] * b[j];
        }
        __syncthreads();
    }
#pragma unroll
    for (int i = 0; i < 4; i++) {
        int m = m0 + ty * 4 + i;
#pragma unroll
        for (int j = 0; j < 4; j++) {
            int n = n0 + tx * 4 + j;
            P[(size_t)m * ldp + n] -= lr * acc[i][j];
        }
    }
}

// ---------------- bias update: b[n] -= lr * colsum(dY) ----------------
__global__ void colsum_update(const float* __restrict__ dY, int ldy, int rows,
                              float* __restrict__ bvec, int cols, float lr) {
    int n = blockIdx.x * blockDim.x + threadIdx.x;
    if (n < cols) {
        float s = 0;
        for (int r = 0; r < rows; r++) s += dY[(size_t)r * ldy + n];
        bvec[n] -= lr * s;
    }
}

// ---------------- attention forward (per b,h) ----------------
__global__ __launch_bounds__(128) void attn_fwd(const float* __restrict__ qkv,
        float* __restrict__ att, float* __restrict__ O) {
    int bh = blockIdx.x, b = bh >> 3, h = bh & 7;
    __shared__ float Ks[128][64];
    __shared__ float Vs[128][64];
    for (int idx = threadIdx.x; idx < 128 * 64; idx += 128) {
        int j = idx >> 6, d = idx & 63;
        int row = b * 128 + j;
        Ks[j][d] = qkv[(size_t)row * 1536 + 512 + h * 64 + d];
        Vs[j][d] = qkv[(size_t)row * 1536 + 1024 + h * 64 + d];
    }
    __syncthreads();
    int i = threadIdx.x;
    int row = b * 128 + i;
    float q[64];
#pragma unroll
    for (int d = 0; d < 64; d++) q[d] = qkv[(size_t)row * 1536 + h * 64 + d];
    float* arow = att + ((size_t)bh * 128 + i) * 128;
    float mmax = -1e30f, ssum = 0.f;
    for (int j = 0; j <= i; j++) {
        float sc = 0;
#pragma unroll
        for (int d = 0; d < 64; d++) sc += q[d] * Ks[j][d];
        sc *= 0.125f;
        arow[j] = sc;
        float mn = fmaxf(mmax, sc);
        ssum = ssum * expf(mmax - mn) + expf(sc - mn);
        mmax = mn;
    }
    float inv = 1.f / ssum;
    float o[64];
#pragma unroll
    for (int d = 0; d < 64; d++) o[d] = 0.f;
    for (int j = 0; j < 128; j++) {
        float p = (j <= i) ? expf(arow[j] - mmax) * inv : 0.f;
        arow[j] = p;
#pragma unroll
        for (int d = 0; d < 64; d++) o[d] += p * Vs[j][d];
    }
#pragma unroll
    for (int d = 0; d < 64; d++) O[(size_t)row * 512 + h * 64 + d] = o[d];
}

// ---------------- attention backward pass 1: dS', dq ----------------
__global__ __launch_bounds__(128) void attn_bwd1(const float* __restrict__ qkv,
        const float* __restrict__ att, const float* __restrict__ dO,
        float* __restrict__ dS, float* __restrict__ dqkv) {
    int bh = blockIdx.x, b = bh >> 3, h = bh & 7;
    __shared__ float Ks[128][64];
    __shared__ float Vs[128][64];
    for (int idx = threadIdx.x; idx < 128 * 64; idx += 128) {
        int j = idx >> 6, d = idx & 63;
        int row = b * 128 + j;
        Ks[j][d] = qkv[(size_t)row * 1536 + 512 + h * 64 + d];
        Vs[j][d] = qkv[(size_t)row * 1536 + 1024 + h * 64 + d];
    }
    __syncthreads();
    int i = threadIdx.x;
    int row = b * 128 + i;
    float dOi[64];
#pragma unroll
    for (int d = 0; d < 64; d++) dOi[d] = dO[(size_t)row * 512 + h * 64 + d];
    const float* arow = att + ((size_t)bh * 128 + i) * 128;
    float* dsrow = dS + ((size_t)bh * 128 + i) * 128;
    float rowdot = 0.f;
    for (int j = 0; j <= i; j++) {
        float dA = 0;
#pragma unroll
        for (int d = 0; d < 64; d++) dA += dOi[d] * Vs[j][d];
        dsrow[j] = dA;
        rowdot += dA * arow[j];
    }
    float dq[64];
#pragma unroll
    for (int d = 0; d < 64; d++) dq[d] = 0.f;
    for (int j = 0; j <= i; j++) {
        float ds = arow[j] * (dsrow[j] - rowdot);
        dsrow[j] = ds;
#pragma unroll
        for (int d = 0; d < 64; d++) dq[d] += ds * Ks[j][d];
    }
    for (int j = i + 1; j < 128; j++) dsrow[j] = 0.f;
#pragma unroll
    for (int d = 0; d < 64; d++)
        dqkv[(size_t)row * 1536 + h * 64 + d] = dq[d] * 0.125f;
}

// ---------------- attention backward pass 2: dk, dv ----------------
__global__ __launch_bounds__(128) void attn_bwd2(const float* __restrict__ qkv,
        const float* __restrict__ att, const float* __restrict__ dS,
        const float* __restrict__ dO, float* __restrict__ dqkv) {
    int bh = blockIdx.x, b = bh >> 3, h = bh & 7;
    __shared__ float Qs[128][64];
    __shared__ float dOs[128][64];
    for (int idx = threadIdx.x; idx < 128 * 64; idx += 128) {
        int j = idx >> 6, d = idx & 63;
        int row = b * 128 + j;
        Qs[j][d] = qkv[(size_t)row * 1536 + h * 64 + d];
        dOs[j][d] = dO[(size_t)row * 512 + h * 64 + d];
    }
    __syncthreads();
    int j = threadIdx.x;
    float dk[64], dv[64];
#pragma unroll
    for (int d = 0; d < 64; d++) { dk[d] = 0.f; dv[d] = 0.f; }
    for (int i = j; i < 128; i++) {
        float a_ = att[((size_t)bh * 128 + i) * 128 + j];
        float ds = dS[((size_t)bh * 128 + i) * 128 + j];
#pragma unroll
        for (int d = 0; d < 64; d++) { dv[d] += a_ * dOs[i][d]; dk[d] += ds * Qs[i][d]; }
    }
    int row = b * 128 + j;
#pragma unroll
    for (int d = 0; d < 64; d++) {
        dqkv[(size_t)row * 1536 + 512 + h * 64 + d] = dk[d] * 0.125f;
        dqkv[(size_t)row * 1536 + 1024 + h * 64 + d] = dv[d];
    }
}

// ---------------- gelu ----------------
__global__ void gelu_fwd(const float* __restrict__ g, float* __restrict__ u, int n) {
    int i = blockIdx.x * blockDim.x + threadIdx.x;
    if (i < n) {
        float x = g[i];
        float t = tanhf(0.7978845608028654f * (x + 0.044715f * x * x * x));
        u[i] = 0.5f * x * (1.f + t);
    }
}

__global__ void gelu_bwd(const float* __restrict__ g, const float* __restrict__ du,
                         float* __restrict__ dg, int n) {
    int i = blockIdx.x * blockDim.x + threadIdx.x;
    if (i < n) {
        float x = g[i];
        const float c = 0.7978845608028654f, a = 0.044715f;
        float t = tanhf(c * (x + a * x * x * x));
        float dt = (1.f - t * t) * c * (1.f + 3.f * a * x * x);
        float grad = 0.5f * (1.f + t) + 0.5f * x * dt;
        dg[i] = du[i] * grad;
    }
}

// ---------------- cross-entropy gradient ----------------
__global__ void ce_grad(const float* __restrict__ logits, const int* __restrict__ x,
                        float* __restrict__ dl, int c) {
    __shared__ float sbuf[8];
    int n = blockIdx.x;
    int b = n >> 7, i = n & 127;
    int tgt = x[b * T + c * MB + i + 1];
    const float* lr = logits + (size_t)n * V;
    float mx = -1e30f;
    for (int v = threadIdx.x; v < V; v += blockDim.x) mx = fmaxf(mx, lr[v]);
    mx = block_max(mx, sbuf);
    float se = 0;
    for (int v = threadIdx.x; v < V; v += blockDim.x) se += expf(lr[v] - mx);
    se = block_sum(se, sbuf);
    float inv = 1.f / se;
    for (int v = threadIdx.x; v < V; v += blockDim.x) {
        float p = expf(lr[v] - mx) * inv;
        dl[(size_t)n * V + v] = (p - (v == tgt ? 1.f : 0.f)) * (1.f / 256.f);
    }
}

// ---------------- scatter logits to output ----------------
__global__ void scatter_logits(const float* __restrict__ lbuf, float* __restrict__ out, int c) {
    size_t idx = (size_t)blockIdx.x * blockDim.x + threadIdx.x;
    if (idx < (size_t)NTOK * V) {
        int n = idx / V, v = idx % V;
        int b = n >> 7, i = n & 127;
        out[((size_t)(b * 1024 + c * MB + i)) * V + v] = lbuf[idx];
    }
}

// ---------------- host orchestration ----------------
extern "C" void kernel_launch(void* const* d_in, const int* in_sizes, int n_in,
                              void* d_out, int out_size, void* d_ws, size_t ws_size,
                              hipStream_t stream) {
    const int* x = (const int*)d_in[0];
    const float* emb = (const float*)d_in[1];
    const float* pos = (const float*)d_in[2];
    const float* ln1_s = (const float*)d_in[3];
    const float* ln1_b = (const float*)d_in[4];
    const float* Wqkv = (const float*)d_in[5];
    const float* bqkv = (const float*)d_in[6];
    const float* Wo = (const float*)d_in[7];
    const float* bo = (const float*)d_in[8];
    const float* ln2_s = (const float*)d_in[9];
    const float* ln2_b = (const float*)d_in[10];
    const float* W1in = (const float*)d_in[11];
    const float* b1in = (const float*)d_in[12];
    const float* W2in = (const float*)d_in[13];
    const float* b2in = (const float*)d_in[14];
    const float* lnf_s = (const float*)d_in[15];
    const float* lnf_b = (const float*)d_in[16];
    const float* Whead = (const float*)d_in[17];
    const float* bhead = (const float*)d_in[18];
    float* out = (float*)d_out;

    float* ws = (float*)d_ws;
    size_t off = 0;
    auto alloc = [&](size_t n) { float* p = ws + off; off += n; return p; };
    float* W1w = alloc((size_t)LAYERS * D * HID);
    float* b1w = alloc((size_t)LAYERS * HID);
    float* W2w = alloc((size_t)LAYERS * HID * D);
    float* b2w = alloc((size_t)LAYERS * D);
    float* h[5]; for (int i = 0; i < 5; i++) h[i] = alloc((size_t)NTOK * D);
    float* hp[4]; for (int i = 0; i < 4; i++) hp[i] = alloc((size_t)NTOK * D);
    float* qkvb[4]; for (int i = 0; i < 4; i++) qkvb[i] = alloc((size_t)NTOK * 3 * D);
    float* attb[4]; for (int i = 0; i < 4; i++) attb[i] = alloc((size_t)BATCH * NH * MB * MB);
    float* mb[4]; for (int i = 0; i < 4; i++) mb[i] = alloc((size_t)NTOK * D);
    float* gbuf[4]; for (int i = 0; i < 4; i++) gbuf[i] = alloc((size_t)NTOK * HID);
    float* ubuf[4]; for (int i = 0; i < 4; i++) ubuf[i] = alloc((size_t)NTOK * HID);
    float* aBuf = alloc((size_t)NTOK * D);
    float* Obuf = alloc((size_t)NTOK * D);
    float* logitsb = alloc((size_t)NTOK * V);
    float* dlog = alloc((size_t)NTOK * V);
    float* dh = alloc((size_t)NTOK * D);
    float* dhp = alloc((size_t)NTOK * D);
    float* t512 = alloc((size_t)NTOK * D);
    float* du = alloc((size_t)NTOK * HID);
    float* dg = alloc((size_t)NTOK * HID);
    float* dqkv = alloc((size_t)NTOK * 3 * D);
    float* dS = alloc((size_t)BATCH * NH * MB * MB);

    // copy mutable MLP params into workspace
    hipMemcpyAsync(W1w, W1in, (size_t)LAYERS * D * HID * 4, hipMemcpyDeviceToDevice, stream);
    hipMemcpyAsync(b1w, b1in, (size_t)LAYERS * HID * 4, hipMemcpyDeviceToDevice, stream);
    hipMemcpyAsync(W2w, W2in, (size_t)LAYERS * HID * D * 4, hipMemcpyDeviceToDevice, stream);
    hipMemcpyAsync(b2w, b2in, (size_t)LAYERS * D * 4, hipMemcpyDeviceToDevice, stream);

    dim3 blk256(256);
    for (int c = 0; c < NCHUNK; c++) {
        // ---------------- forward ----------------
        embed_kernel<<<NTOK, blk256, 0, stream>>>(x, emb, pos, h[0], c);
        for (int l = 0; l < LAYERS; l++) {
            ln_fwd<<<NTOK, blk256, 0, stream>>>(h[l], ln1_s + l * D, ln1_b + l * D, aBuf);
            gemm_nn<<<dim3(1536 / 64, NTOK / 64), blk256, 0, stream>>>(
                aBuf, D, Wqkv + (size_t)l * D * 1536, 1536, qkvb[l], 1536, D,
                bqkv + l * 1536, nullptr, 0);
            attn_fwd<<<16, 128, 0, stream>>>(qkvb[l], attb[l], Obuf);
            gemm_nn<<<dim3(D / 64, NTOK / 64), blk256, 0, stream>>>(
                Obuf, D, Wo + (size_t)l * D * D, D, hp[l], D, D,
                bo + l * D, h[l], D);
            ln_fwd<<<NTOK, blk256, 0, stream>>>(hp[l], ln2_s + l * D, ln2_b + l * D, mb[l]);
            gemm_nn<<<dim3(HID / 64, NTOK / 64), blk256, 0, stream>>>(
                mb[l], D, W1w + (size_t)l * D * HID, HID, gbuf[l], HID, D,
                b1w + l * HID, nullptr, 0);
            gelu_fwd<<<(NTOK * HID) / 256, blk256, 0, stream>>>(gbuf[l], ubuf[l], NTOK * HID);
            gemm_nn<<<dim3(D / 64, NTOK / 64), blk256, 0, stream>>>(
                ubuf[l], HID, W2w + (size_t)l * HID * D, D, h[l + 1], D, HID,
                b2w + l * D, hp[l], D);
        }
        ln_fwd<<<NTOK, blk256, 0, stream>>>(h[4], lnf_s, lnf_b, aBuf);
        gemm_nn<<<dim3(V / 64, NTOK / 64), blk256, 0, stream>>>(
            aBuf, D, Whead, V, logitsb, V, D, bhead, nullptr, 0);
        scatter_logits<<<(NTOK * V) / 256, blk256, 0, stream>>>(logitsb, out, c);

        // ---------------- backward ----------------
        ce_grad<<<NTOK, blk256, 0, stream>>>(logitsb, x, dlog, c);
        gemm_nt<<<dim3(D / 64, NTOK / 64), blk256, 0, stream>>>(dlog, V, Whead, V, t512, D, V);
        ln_bwd<<<NTOK, blk256, 0, stream>>>(t512, h[4], lnf_s, nullptr, dh);
        for (int l = LAYERS - 1; l >= 0; l--) {
            // MLP backward
            gemm_nt<<<dim3(HID / 64, NTOK / 64), blk256, 0, stream>>>(
                dh, D, W2w + (size_t)l * HID * D, D, du, HID, D);
            gemm_tn_update<<<dim3(D / 64, HID / 64), blk256, 0, stream>>>(
                ubuf[l], HID, dh, D, W2w + (size_t)l * HID * D, D, NTOK, LR);
            colsum_update<<<(D + 255) / 256, blk256, 0, stream>>>(dh, D, NTOK, b2w + l * D, D, LR);
            gelu_bwd<<<(NTOK * HID) / 256, blk256, 0, stream>>>(gbuf[l], du, dg, NTOK * HID);
            gemm_nt<<<dim3(D / 64, NTOK / 64), blk256, 0, stream>>>(
                dg, HID, W1w + (size_t)l * D * HID, HID, t512, D, HID);
            gemm_tn_update<<<dim3(HID / 64, D / 64), blk256, 0, stream>>>(
                mb[l], D, dg, HID, W1w + (size_t)l * D * HID, HID, NTOK, LR);
            colsum_update<<<(HID + 255) / 256, blk256, 0, stream>>>(dg, HID, NTOK, b1w + l * HID, HID, LR);
            ln_bwd<<<NTOK, blk256, 0, stream>>>(t512, hp[l], ln2_s + l * D, dh, dhp);
            // attention backward
            gemm_nt<<<dim3(D / 64, NTOK / 64), blk256, 0, stream>>>(
                dhp, D, Wo + (size_t)l * D * D, D, t512, D, D);
            attn_bwd1<<<16, 128, 0, stream>>>(qkvb[l], attb[l], t512, dS, dqkv);
            attn_bwd2<<<16, 128, 0, stream>>>(qkvb[l], attb[l], dS, t512, dqkv);
            gemm_nt<<<dim3(D / 64, NTOK / 64), blk256, 0, stream>>>(
                dqkv, 1536, Wqkv + (size_t)l * D * 1536, 1536, t512, D, 1536);
            ln_bwd<<<NTOK, blk256, 0, stream>>>(t512, h[l], ln1_s + l * D, dhp, dh);
        }
    }
}

// Round 2
// 18498.700 us; speedup vs baseline: 3.6830x; 3.6830x over previous
//
#include <hip/hip_runtime.h>
#include <hip/hip_bf16.h>
#include <math.h>

#define D 512
#define HID 2048
#define LAYERS 4
#define V 32000
#define BATCH 2
#define T 1025
#define MB 128
#define NH 8
#define DH 64
#define NTOK 256            // BATCH*MB rows per chunk
#define LR 0.0003f
#define NCHUNK 8
#define SPLITK 20
#define SKLEN 1600          // 32000 / 20, multiple of 64

typedef unsigned short u16;
typedef __attribute__((ext_vector_type(8))) short bf16x8;
typedef __attribute__((ext_vector_type(4))) float f32x4;

// ---- fp32 <-> bf16 (RNE) ----
__device__ __forceinline__ u16 f2b(float f) {
    unsigned int x = __float_as_uint(f);
    unsigned int r = (x + 0x7FFFu + ((x >> 16) & 1u)) >> 16;
    return (u16)r;
}
__device__ __forceinline__ float b2f(u16 u) {
    return __uint_as_float(((unsigned int)u) << 16);
}

// ---- async global->LDS 16B ----
__device__ __forceinline__ void gload16(const u16* g, u16* l) {
    __builtin_amdgcn_global_load_lds(
        (const __attribute__((address_space(1))) unsigned int*)g,
        (__attribute__((address_space(3))) unsigned int*)l, 16, 0, 0);
}

// =================== MFMA GEMM core ===================
// C[M][N] = A[M][K] * Bt[N][K]^T ; A,Bt bf16 K-contiguous. 64x64 tile, BK=64.
// LDS XOR-swizzle (quad granularity) keeps global_load_lds lane-contiguity AND
// conflict-free ds_read_b128 fragment loads (2-way max, free per m136).
__device__ __forceinline__ void gemm_core(
    const u16* __restrict__ A, int lda, const u16* __restrict__ Bt, int ldb,
    int kBegin, int kEnd, int m0, int n0, u16* As, u16* Bs, f32x4 acc[2][2])
{
    int t = threadIdx.x, w = t >> 6, l = t & 63;
    int srow = w * 8 + (l >> 3);     // staging row 0..31 (+32 second half)
    int qs = l & 7;                  // LDS quad slot
    int gq = qs ^ (srow & 7);        // swizzled global quad
    const u16* Ag = A + (size_t)(m0 + srow) * lda + gq * 8;
    const u16* Bg = Bt + (size_t)(n0 + srow) * ldb + gq * 8;
    u16* AsP = As + srow * 64 + qs * 8;
    u16* BsP = Bs + srow * 64 + qs * 8;
    size_t a32 = (size_t)32 * lda, b32 = (size_t)32 * ldb;
    int fr = l & 15, fq = l >> 4;
    int wr = (w >> 1) * 32, wc = (w & 1) * 32;  // wave sub-tile
    const u16* arp = As + (size_t)(wr + fr) * 64;
    const u16* brp = Bs + (size_t)(wc + fr) * 64;
    int sw = fr & 7;
    for (int k0 = kBegin; k0 < kEnd; k0 += 64) {
        if (k0 != kBegin) __syncthreads();
        gload16(Ag + k0, AsP);
        gload16(Ag + a32 + k0, AsP + 32 * 64);
        gload16(Bg + k0, BsP);
        gload16(Bg + b32 + k0, BsP + 32 * 64);
        __syncthreads();   // compiler emits vmcnt(0) drain before s_barrier
#pragma unroll
        for (int kk = 0; kk < 2; kk++) {
            int sq = ((kk * 4 + fq) ^ sw) * 8;
            bf16x8 a0 = *(const bf16x8*)(arp + sq);
            bf16x8 a1 = *(const bf16x8*)(arp + 16 * 64 + sq);
            bf16x8 b0 = *(const bf16x8*)(brp + sq);
            bf16x8 b1 = *(const bf16x8*)(brp + 16 * 64 + sq);
            acc[0][0] = __builtin_amdgcn_mfma_f32_16x16x32_bf16(a0, b0, acc[0][0], 0, 0, 0);
            acc[0][1] = __builtin_amdgcn_mfma_f32_16x16x32_bf16(a0, b1, acc[0][1], 0, 0, 0);
            acc[1][0] = __builtin_amdgcn_mfma_f32_16x16x32_bf16(a1, b0, acc[1][0], 0, 0, 0);
            acc[1][1] = __builtin_amdgcn_mfma_f32_16x16x32_bf16(a1, b1, acc[1][1], 0, 0, 0);
        }
    }
}

// generic GEMM: optional bias, residual, chunk-row-remap, split-K partials
__global__ __launch_bounds__(256) void gemm64(
    const u16* __restrict__ A, int lda, const u16* __restrict__ Bt, int ldb,
    float* __restrict__ C, int ldc, int kLen, int zStride,
    const float* __restrict__ bias, const float* __restrict__ res, int ldres, int remapc)
{
    __shared__ __align__(16) u16 As[64 * 64];
    __shared__ __align__(16) u16 Bs[64 * 64];
    f32x4 zero = {0.f, 0.f, 0.f, 0.f};
    f32x4 acc[2][2] = {{zero, zero}, {zero, zero}};
    int z = blockIdx.z;
    int m0 = blockIdx.y * 64, n0 = blockIdx.x * 64;
    gemm_core(A, lda, Bt, ldb, z * kLen, z * kLen + kLen, m0, n0, As, Bs, acc);
    float* Cz = C + (size_t)z * zStride;
    int l = threadIdx.x & 63, w = threadIdx.x >> 6;
    int wr = (w >> 1) * 32, wc = (w & 1) * 32;
    int cn = n0 + wc + (l & 15);
    int rb = wr + (l >> 4) * 4;
#pragma unroll
    for (int i = 0; i < 2; i++)
#pragma unroll
        for (int r = 0; r < 4; r++) {
            int m = m0 + rb + i * 16 + r;
            int mo = (remapc >= 0) ? ((m >> 7) * 1024 + remapc * 128 + (m & 127)) : m;
#pragma unroll
            for (int j = 0; j < 2; j++) {
                int n = cn + j * 16;
                float v = acc[i][j][r];
                if (bias) v += bias[n];
                if (res) v += res[(size_t)m * ldres + n];
                Cz[(size_t)mo * ldc + n] = v;
            }
        }
}

// TN weight-update GEMM: P[m][n] -= lr*acc; refresh bf16 natural+transposed copies
__global__ __launch_bounds__(256) void gemm64_upd(
    const u16* __restrict__ A, int lda, const u16* __restrict__ Bt, int ldb,
    float* __restrict__ P, int ldp, int K, float lr,
    u16* __restrict__ Wn, u16* __restrict__ Wt, int ldt)
{
    __shared__ __align__(16) u16 As[64 * 64];
    __shared__ __align__(16) u16 Bs[64 * 64];
    f32x4 zero = {0.f, 0.f, 0.f, 0.f};
    f32x4 acc[2][2] = {{zero, zero}, {zero, zero}};
    int m0 = blockIdx.y * 64, n0 = blockIdx.x * 64;
    gemm_core(A, lda, Bt, ldb, 0, K, m0, n0, As, Bs, acc);
    int l = threadIdx.x & 63, w = threadIdx.x >> 6;
    int wr = (w >> 1) * 32, wc = (w & 1) * 32;
    int cn = n0 + wc + (l & 15);
    int rb = wr + (l >> 4) * 4;
#pragma unroll
    for (int i = 0; i < 2; i++)
#pragma unroll
        for (int r = 0; r < 4; r++) {
            int m = m0 + rb + i * 16 + r;
#pragma unroll
            for (int j = 0; j < 2; j++) {
                int n = cn + j * 16;
                size_t ip = (size_t)m * ldp + n;
                float nv = P[ip] - lr * acc[i][j][r];
                P[ip] = nv;
                u16 bb = f2b(nv);
                Wn[ip] = bb;
                Wt[(size_t)n * ldt + m] = bb;
            }
        }
}

__global__ void reduce_splitk(const float* __restrict__ Cpart, float* __restrict__ o, int n) {
    int i = blockIdx.x * blockDim.x + threadIdx.x;
    if (i < n) {
        float s = 0.f;
        for (int z = 0; z < SPLITK; z++) s += Cpart[(size_t)z * n + i];
        o[i] = s;
    }
}

// ---- fp32 [R][C] -> bf16 natural [R][C] + bf16 transposed [C][R], 64x64 tiles ----
__global__ __launch_bounds__(256) void conv_nt(const float* __restrict__ in,
        u16* __restrict__ outN, u16* __restrict__ outT, int R, int C) {
    __shared__ u16 Ts[64][72];
    int c0 = blockIdx.x * 64, r0 = blockIdx.y * 64;
    int t = threadIdx.x, lr = t >> 2, cs = (t & 3) * 16;
    const float* ip = in + (size_t)(r0 + lr) * C + c0 + cs;
    u16* op = outN + (size_t)(r0 + lr) * C + c0 + cs;
#pragma unroll
    for (int k = 0; k < 16; k++) {
        u16 bb = f2b(ip[k]);
        op[k] = bb;
        Ts[lr][cs + k] = bb;
    }
    __syncthreads();
    int cc = t >> 2, rs = (t & 3) * 16;
    u16* opT = outT + (size_t)(c0 + cc) * R + r0 + rs;
#pragma unroll
    for (int k = 0; k < 16; k++) opT[k] = Ts[rs + k][cc];
}

// ---------------- reductions ----------------
__device__ __forceinline__ float block_sum(float v, float* sbuf) {
    int t = threadIdx.x;
    for (int o = 32; o > 0; o >>= 1) v += __shfl_down(v, o, 64);
    if ((t & 63) == 0) sbuf[t >> 6] = v;
    __syncthreads();
    int nw = blockDim.x >> 6;
    float r = (t < nw) ? sbuf[t] : 0.f;
    if (t < 64) { for (int o = 32; o > 0; o >>= 1) r += __shfl_down(r, o, 64); }
    if (t == 0) sbuf[0] = r;
    __syncthreads();
    float out = sbuf[0];
    __syncthreads();
    return out;
}
__device__ __forceinline__ float block_max(float v, float* sbuf) {
    int t = threadIdx.x;
    for (int o = 32; o > 0; o >>= 1) v = fmaxf(v, __shfl_down(v, o, 64));
    if ((t & 63) == 0) sbuf[t >> 6] = v;
    __syncthreads();
    int nw = blockDim.x >> 6;
    float r = (t < nw) ? sbuf[t] : -1e30f;
    if (t < 64) { for (int o = 32; o > 0; o >>= 1) r = fmaxf(r, __shfl_down(r, o, 64)); }
    if (t == 0) sbuf[0] = r;
    __syncthreads();
    float out = sbuf[0];
    __syncthreads();
    return out;
}

// ---------------- embedding ----------------
__global__ void embed_kernel(const int* __restrict__ x, const float* __restrict__ emb,
                             const float* __restrict__ pos, float* __restrict__ h0, int c) {
    int n = blockIdx.x;
    int b = n >> 7, i = n & 127;
    int tok = x[b * T + c * MB + i];
    for (int d = threadIdx.x; d < D; d += blockDim.x)
        h0[(size_t)n * D + d] = emb[(size_t)tok * D + d] + pos[(size_t)i * D + d];
}

// ---------------- layernorm fwd (bf16 out, optional bf16^T out) ----------------
__global__ void ln_fwd(const float* __restrict__ x, const float* __restrict__ s,
                       const float* __restrict__ bb, u16* __restrict__ y,
                       u16* __restrict__ yT) {
    __shared__ float sbuf[8];
    int row = blockIdx.x;
    const float* xr = x + (size_t)row * D;
    float sum = 0;
    for (int d = threadIdx.x; d < D; d += blockDim.x) sum += xr[d];
    float mean = block_sum(sum, sbuf) / D;
    float vs = 0;
    for (int d = threadIdx.x; d < D; d += blockDim.x) { float t = xr[d] - mean; vs += t * t; }
    float var = block_sum(vs, sbuf) / D;
    float rstd = rsqrtf(var + 1e-5f);
    for (int d = threadIdx.x; d < D; d += blockDim.x) {
        float v = (xr[d] - mean) * rstd * s[d] + bb[d];
        u16 b16 = f2b(v);
        y[(size_t)row * D + d] = b16;
        if (yT) yT[(size_t)d * NTOK + row] = b16;
    }
}

// ---------------- layernorm bwd ----------------
__global__ void ln_bwd(const float* __restrict__ dy, const float* __restrict__ x,
                       const float* __restrict__ s, const float* __restrict__ addend,
                       float* __restrict__ dx, u16* __restrict__ dxb, u16* __restrict__ dxT) {
    __shared__ float sbuf[8];
    int row = blockIdx.x;
    const float* xr = x + (size_t)row * D;
    const float* dyr = dy + (size_t)row * D;
    float sum = 0;
    for (int d = threadIdx.x; d < D; d += blockDim.x) sum += xr[d];
    float mean = block_sum(sum, sbuf) / D;
    float vs = 0;
    for (int d = threadIdx.x; d < D; d += blockDim.x) { float t = xr[d] - mean; vs += t * t; }
    float var = block_sum(vs, sbuf) / D;
    float rstd = rsqrtf(var + 1e-5f);
    float d1 = 0, d2 = 0;
    for (int d = threadIdx.x; d < D; d += blockDim.x) {
        float xh = (xr[d] - mean) * rstd;
        float t1 = s[d] * dyr[d];
        d1 += t1; d2 += t1 * xh;
    }
    float dot1 = block_sum(d1, sbuf);
    float dot2 = block_sum(d2, sbuf);
    for (int d = threadIdx.x; d < D; d += blockDim.x) {
        float xh = (xr[d] - mean) * rstd;
        float t1 = s[d] * dyr[d];
        float v = rstd * (t1 - (dot1 + xh * dot2) * (1.f / D));
        if (addend) v += addend[(size_t)row * D + d];
        if (dx) dx[(size_t)row * D + d] = v;
        u16 b16 = f2b(v);
        if (dxb) dxb[(size_t)row * D + d] = b16;
        if (dxT) dxT[(size_t)d * NTOK + row] = b16;
    }
}

// ---------------- bias update from bf16 grads ----------------
__global__ void colsum_bf(const u16* __restrict__ dY, int ldy, int rows,
                          float* __restrict__ bvec, int cols, float lr) {
    int n = blockIdx.x * blockDim.x + threadIdx.x;
    if (n < cols) {
        float s = 0;
        for (int r = 0; r < rows; r++) s += b2f(dY[(size_t)r * ldy + n]);
        bvec[n] -= lr * s;
    }
}

// ---------------- attention forward (fp32 core, bf16 O) ----------------
__global__ __launch_bounds__(128) void attn_fwd(const float* __restrict__ qkv,
        float* __restrict__ att, u16* __restrict__ O) {
    int bh = blockIdx.x, b = bh >> 3, h = bh & 7;
    __shared__ float Ks[128][64];
    __shared__ float Vs[128][64];
    for (int idx = threadIdx.x; idx < 128 * 64; idx += 128) {
        int j = idx >> 6, d = idx & 63;
        int row = b * 128 + j;
        Ks[j][d] = qkv[(size_t)row * 1536 + 512 + h * 64 + d];
        Vs[j][d] = qkv[(size_t)row * 1536 + 1024 + h * 64 + d];
    }
    __syncthreads();
    int i = threadIdx.x;
    int row = b * 128 + i;
    float q[64];
#pragma unroll
    for (int d = 0; d < 64; d++) q[d] = qkv[(size_t)row * 1536 + h * 64 + d];
    float* arow = att + ((size_t)bh * 128 + i) * 128;
    float mmax = -1e30f, ssum = 0.f;
    for (int j = 0; j <= i; j++) {
        float sc = 0;
#pragma unroll
        for (int d = 0; d < 64; d++) sc += q[d] * Ks[j][d];
        sc *= 0.125f;
        arow[j] = sc;
        float mn = fmaxf(mmax, sc);
        ssum = ssum * expf(mmax - mn) + expf(sc - mn);
        mmax = mn;
    }
    float inv = 1.f / ssum;
    float o[64];
#pragma unroll
    for (int d = 0; d < 64; d++) o[d] = 0.f;
    for (int j = 0; j < 128; j++) {
        float p = (j <= i) ? expf(arow[j] - mmax) * inv : 0.f;
        arow[j] = p;
#pragma unroll
        for (int d = 0; d < 64; d++) o[d] += p * Vs[j][d];
    }
#pragma unroll
    for (int d = 0; d < 64; d++) O[(size_t)row * 512 + h * 64 + d] = f2b(o[d]);
}

// ---------------- attention backward 1: dS, dq (bf16 out) ----------------
__global__ __launch_bounds__(128) void attn_bwd1(const float* __restrict__ qkv,
        const float* __restrict__ att, const float* __restrict__ dO,
        float* __restrict__ dS, u16* __restrict__ dqkv) {
    int bh = blockIdx.x, b = bh >> 3, h = bh & 7;
    __shared__ float Ks[128][64];
    __shared__ float Vs[128][64];
    for (int idx = threadIdx.x; idx < 128 * 64; idx += 128) {
        int j = idx >> 6, d = idx & 63;
        int row = b * 128 + j;
        Ks[j][d] = qkv[(size_t)row * 1536 + 512 + h * 64 + d];
        Vs[j][d] = qkv[(size_t)row * 1536 + 1024 + h * 64 + d];
    }
    __syncthreads();
    int i = threadIdx.x;
    int row = b * 128 + i;
    float dOi[64];
#pragma unroll
    for (int d = 0; d < 64; d++) dOi[d] = dO[(size_t)row * 512 + h * 64 + d];
    const float* arow = att + ((size_t)bh * 128 + i) * 128;
    float* dsrow = dS + ((size_t)bh * 128 + i) * 128;
    float rowdot = 0.f;
    for (int j = 0; j <= i; j++) {
        float dA = 0;
#pragma unroll
        for (int d = 0; d < 64; d++) dA += dOi[d] * Vs[j][d];
        dsrow[j] = dA;
        rowdot += dA * arow[j];
    }
    float dq[64];
#pragma unroll
    for (int d = 0; d < 64; d++) dq[d] = 0.f;
    for (int j = 0; j <= i; j++) {
        float ds = arow[j] * (dsrow[j] - rowdot);
        dsrow[j] = ds;
#pragma unroll
        for (int d = 0; d < 64; d++) dq[d] += ds * Ks[j][d];
    }
    for (int j = i + 1; j < 128; j++) dsrow[j] = 0.f;
#pragma unroll
    for (int d = 0; d < 64; d++)
        dqkv[(size_t)row * 1536 + h * 64 + d] = f2b(dq[d] * 0.125f);
}

// ---------------- attention backward 2: dk, dv (bf16 out) ----------------
__global__ __launch_bounds__(128) void attn_bwd2(const float* __restrict__ qkv,
        const float* __restrict__ att, const float* __restrict__ dS,
        const float* __restrict__ dO, u16* __restrict__ dqkv) {
    int bh = blockIdx.x, b = bh >> 3, h = bh & 7;
    __shared__ float Qs[128][64];
    __shared__ float dOs[128][64];
    for (int idx = threadIdx.x; idx < 128 * 64; idx += 128) {
        int j = idx >> 6, d = idx & 63;
        int row = b * 128 + j;
        Qs[j][d] = qkv[(size_t)row * 1536 + h * 64 + d];
        dOs[j][d] = dO[(size_t)row * 512 + h * 64 + d];
    }
    __syncthreads();
    int j = threadIdx.x;
    float dk[64], dv[64];
#pragma unroll
    for (int d = 0; d < 64; d++) { dk[d] = 0.f; dv[d] = 0.f; }
    for (int i = j; i < 128; i++) {
        float a_ = att[((size_t)bh * 128 + i) * 128 + j];
        float ds = dS[((size_t)bh * 128 + i) * 128 + j];
#pragma unroll
        for (int d = 0; d < 64; d++) { dv[d] += a_ * dOs[i][d]; dk[d] += ds * Qs[i][d]; }
    }
    int row = b * 128 + j;
#pragma unroll
    for (int d = 0; d < 64; d++) {
        dqkv[(size_t)row * 1536 + 512 + h * 64 + d] = f2b(dk[d] * 0.125f);
        dqkv[(size_t)row * 1536 + 1024 + h * 64 + d] = f2b(dv[d]);
    }
}

// ---------------- gelu fwd: fp32 in -> bf16 + bf16^T (tiled transpose) ----------------
__global__ __launch_bounds__(256) void gelu_fwd(const float* __restrict__ g,
        u16* __restrict__ u, u16* __restrict__ uT) {
    __shared__ u16 Ts[64][72];
    int c0 = blockIdx.x * 64, r0 = blockIdx.y * 64;
    int t = threadIdx.x, lr = t >> 2, cs = (t & 3) * 16;
    const float* ip = g + (size_t)(r0 + lr) * HID + c0 + cs;
    u16* op = u + (size_t)(r0 + lr) * HID + c0 + cs;
#pragma unroll
    for (int k = 0; k < 16; k++) {
        float x = ip[k];
        float th = tanhf(0.7978845608028654f * (x + 0.044715f * x * x * x));
        u16 bb = f2b(0.5f * x * (1.f + th));
        op[k] = bb;
        Ts[lr][cs + k] = bb;
    }
    __syncthreads();
    int cc = t >> 2, rs = (t & 3) * 16;
    u16* opT = uT + (size_t)(c0 + cc) * NTOK + r0 + rs;
#pragma unroll
    for (int k = 0; k < 16; k++) opT[k] = Ts[rs + k][cc];
}

// ---------------- gelu bwd: fp32 g, fp32 du -> bf16 dg + bf16 dg^T ----------------
__global__ __launch_bounds__(256) void gelu_bwd(const float* __restrict__ g,
        const float* __restrict__ du, u16* __restrict__ dg, u16* __restrict__ dgT) {
    __shared__ u16 Ts[64][72];
    int c0 = blockIdx.x * 64, r0 = blockIdx.y * 64;
    int t = threadIdx.x, lr = t >> 2, cs = (t & 3) * 16;
    size_t base = (size_t)(r0 + lr) * HID + c0 + cs;
    const float* ip = g + base;
    const float* dp = du + base;
    u16* op = dg + base;
#pragma unroll
    for (int k = 0; k < 16; k++) {
        float x = ip[k];
        const float cc_ = 0.7978845608028654f, a = 0.044715f;
        float th = tanhf(cc_ * (x + a * x * x * x));
        float dt = (1.f - th * th) * cc_ * (1.f + 3.f * a * x * x);
        float grad = 0.5f * (1.f + th) + 0.5f * x * dt;
        u16 bb = f2b(dp[k] * grad);
        op[k] = bb;
        Ts[lr][cs + k] = bb;
    }
    __syncthreads();
    int cc = t >> 2, rs = (t & 3) * 16;
    u16* opT = dgT + (size_t)(c0 + cc) * NTOK + r0 + rs;
#pragma unroll
    for (int k = 0; k < 16; k++) opT[k] = Ts[rs + k][cc];
}

// ---------------- cross-entropy gradient (reads logits from d_out, bf16 out) ----------------
__global__ void ce_grad(const float* __restrict__ outbuf, const int* __restrict__ x,
                        u16* __restrict__ dl, int c) {
    __shared__ float sbuf[8];
    int n = blockIdx.x;
    int b = n >> 7, i = n & 127;
    int tgt = x[b * T + c * MB + i + 1];
    const float* lrow = outbuf + ((size_t)(b * 1024 + c * MB + i)) * V;
    float mx = -1e30f;
    for (int v = threadIdx.x; v < V; v += blockDim.x) mx = fmaxf(mx, lrow[v]);
    mx = block_max(mx, sbuf);
    float se = 0;
    for (int v = threadIdx.x; v < V; v += blockDim.x) se += expf(lrow[v] - mx);
    se = block_sum(se, sbuf);
    float inv = 1.f / se;
    for (int v = threadIdx.x; v < V; v += blockDim.x) {
        float p = expf(lrow[v] - mx) * inv;
        dl[(size_t)n * V + v] = f2b((p - (v == tgt ? 1.f : 0.f)) * (1.f / 256.f));
    }
}

// ---------------- host orchestration ----------------
extern "C" void kernel_launch(void* const* d_in, const int* in_sizes, int n_in,
                              void* d_out, int out_size, void* d_ws, size_t ws_size,
                              hipStream_t stream) {
    const int* x = (const int*)d_in[0];
    const float* emb = (const float*)d_in[1];
    const float* pos = (const float*)d_in[2];
    const float* ln1_s = (const float*)d_in[3];
    const float* ln1_b = (const float*)d_in[4];
    const float* Wqkv = (const float*)d_in[5];
    const float* bqkv = (const float*)d_in[6];
    const float* Wo = (const float*)d_in[7];
    const float* bo = (const float*)d_in[8];
    const float* ln2_s = (const float*)d_in[9];
    const float* ln2_b = (const float*)d_in[10];
    const float* W1in = (const float*)d_in[11];
    const float* b1in = (const float*)d_in[12];
    const float* W2in = (const float*)d_in[13];
    const float* b2in = (const float*)d_in[14];
    const float* lnf_s = (const float*)d_in[15];
    const float* lnf_b = (const float*)d_in[16];
    const float* Whead = (const float*)d_in[17];
    const float* bhead = (const float*)d_in[18];
    float* out = (float*)d_out;

    float* ws = (float*)d_ws;
    size_t off = 0;
    auto alloc4 = [&](size_t n) { float* p = ws + off; off += (n + 3) & ~(size_t)3; return p; };
    auto allocH = [&](size_t n) { return (u16*)alloc4((n + 1) / 2); };

    // fp32 masters for trained params
    float* W1m = alloc4((size_t)LAYERS * D * HID);
    float* W2m = alloc4((size_t)LAYERS * HID * D);
    float* b1w = alloc4((size_t)LAYERS * HID);
    float* b2w = alloc4((size_t)LAYERS * D);
    // bf16 weight copies (natural + transposed)
    u16* W1n = allocH((size_t)LAYERS * D * HID);
    u16* W1t = allocH((size_t)LAYERS * D * HID);
    u16* W2n = allocH((size_t)LAYERS * HID * D);
    u16* W2t = allocH((size_t)LAYERS * HID * D);
    u16* Wqkv_n = allocH((size_t)LAYERS * D * 3 * D);
    u16* Wqkv_t = allocH((size_t)LAYERS * D * 3 * D);
    u16* Wo_n = allocH((size_t)LAYERS * D * D);
    u16* Wo_t = allocH((size_t)LAYERS * D * D);
    u16* Whead_n = allocH((size_t)D * V);
    u16* Whead_t = allocH((size_t)D * V);
    // activations
    float* h[5]; for (int i = 0; i < 5; i++) h[i] = alloc4((size_t)NTOK * D);
    float* hp[4]; for (int i = 0; i < 4; i++) hp[i] = alloc4((size_t)NTOK * D);
    u16* a_bf = allocH((size_t)NTOK * D);
    float* qkvb[4]; for (int i = 0; i < 4; i++) qkvb[i] = alloc4((size_t)NTOK * 3 * D);
    float* attb[4]; for (int i = 0; i < 4; i++) attb[i] = alloc4((size_t)BATCH * NH * MB * MB);
    u16* O_bf = allocH((size_t)NTOK * D);
    u16* mb_bf[4]; for (int i = 0; i < 4; i++) mb_bf[i] = allocH((size_t)NTOK * D);
    u16* mbT[4]; for (int i = 0; i < 4; i++) mbT[i] = allocH((size_t)D * NTOK);
    float* gbuf[4]; for (int i = 0; i < 4; i++) gbuf[i] = alloc4((size_t)NTOK * HID);
    u16* u_bf[4]; for (int i = 0; i < 4; i++) u_bf[i] = allocH((size_t)NTOK * HID);
    u16* uT[4]; for (int i = 0; i < 4; i++) uT[i] = allocH((size_t)HID * NTOK);
    u16* af_bf = allocH((size_t)NTOK * D);
    u16* dlog_bf = allocH((size_t)NTOK * V);
    float* Cpart = alloc4((size_t)SPLITK * NTOK * D);
    float* t512 = alloc4((size_t)NTOK * D);
    float* dh = alloc4((size_t)NTOK * D);
    u16* dh_bf = allocH((size_t)NTOK * D);
    u16* dhT = allocH((size_t)D * NTOK);
    float* dhp = alloc4((size_t)NTOK * D);
    u16* dhp_bf = allocH((size_t)NTOK * D);
    float* du = alloc4((size_t)NTOK * HID);
    u16* dg_bf = allocH((size_t)NTOK * HID);
    u16* dgT = allocH((size_t)HID * NTOK);
    u16* dqkv_bf = allocH((size_t)NTOK * 3 * D);
    float* dS = alloc4((size_t)BATCH * NH * MB * MB);

    dim3 blk256(256);

    // ---- one-time (per launch) weight conversions ----
    hipMemcpyAsync(W1m, W1in, (size_t)LAYERS * D * HID * 4, hipMemcpyDeviceToDevice, stream);
    hipMemcpyAsync(W2m, W2in, (size_t)LAYERS * HID * D * 4, hipMemcpyDeviceToDevice, stream);
    hipMemcpyAsync(b1w, b1in, (size_t)LAYERS * HID * 4, hipMemcpyDeviceToDevice, stream);
    hipMemcpyAsync(b2w, b2in, (size_t)LAYERS * D * 4, hipMemcpyDeviceToDevice, stream);
    for (int l = 0; l < LAYERS; l++) {
        conv_nt<<<dim3(1536 / 64, 512 / 64), blk256, 0, stream>>>(
            Wqkv + (size_t)l * D * 1536, Wqkv_n + (size_t)l * D * 1536,
            Wqkv_t + (size_t)l * D * 1536, 512, 1536);
        conv_nt<<<dim3(8, 8), blk256, 0, stream>>>(
            Wo + (size_t)l * D * D, Wo_n + (size_t)l * D * D,
            Wo_t + (size_t)l * D * D, 512, 512);
        conv_nt<<<dim3(32, 8), blk256, 0, stream>>>(
            W1in + (size_t)l * D * HID, W1n + (size_t)l * D * HID,
            W1t + (size_t)l * D * HID, 512, 2048);
        conv_nt<<<dim3(8, 32), blk256, 0, stream>>>(
            W2in + (size_t)l * HID * D, W2n + (size_t)l * HID * D,
            W2t + (size_t)l * HID * D, 2048, 512);
    }
    conv_nt<<<dim3(500, 8), blk256, 0, stream>>>(Whead, Whead_n, Whead_t, 512, 32000);

    // gemm helper: C = A[MxK] * Bt[NxK]^T
    auto G = [&](const u16* A, int lda, const u16* Bt, int ldb, float* C, int ldc,
                 int M, int N, int K, const float* bias, const float* res, int ldres,
                 int remapc) {
        gemm64<<<dim3(N / 64, M / 64), blk256, 0, stream>>>(
            A, lda, Bt, ldb, C, ldc, K, 0, bias, res, ldres, remapc);
    };

    for (int c = 0; c < NCHUNK; c++) {
        // ================ forward ================
        embed_kernel<<<NTOK, blk256, 0, stream>>>(x, emb, pos, h[0], c);
        for (int l = 0; l < LAYERS; l++) {
            ln_fwd<<<NTOK, blk256, 0, stream>>>(h[l], ln1_s + l * D, ln1_b + l * D, a_bf, nullptr);
            G(a_bf, D, Wqkv_t + (size_t)l * D * 1536, D, qkvb[l], 1536,
              NTOK, 1536, D, bqkv + l * 1536, nullptr, 0, -1);
            attn_fwd<<<16, 128, 0, stream>>>(qkvb[l], attb[l], O_bf);
            G(O_bf, D, Wo_t + (size_t)l * D * D, D, hp[l], D,
              NTOK, D, D, bo + l * D, h[l], D, -1);
            ln_fwd<<<NTOK, blk256, 0, stream>>>(hp[l], ln2_s + l * D, ln2_b + l * D,
                                                mb_bf[l], mbT[l]);
            G(mb_bf[l], D, W1t + (size_t)l * D * HID, D, gbuf[l], HID,
              NTOK, HID, D, b1w + l * HID, nullptr, 0, -1);
            gelu_fwd<<<dim3(HID / 64, NTOK / 64), blk256, 0, stream>>>(gbuf[l], u_bf[l], uT[l]);
            G(u_bf[l], HID, W2t + (size_t)l * D * HID, HID, h[l + 1], D,
              NTOK, D, HID, b2w + l * D, hp[l], D, -1);
        }
        ln_fwd<<<NTOK, blk256, 0, stream>>>(h[4], lnf_s, lnf_b, af_bf, nullptr);
        // head GEMM writes directly into d_out with chunk row remap
        G(af_bf, D, Whead_t, D, out, V, NTOK, V, D, bhead, nullptr, 0, c);

        // ================ backward ================
        ce_grad<<<NTOK, blk256, 0, stream>>>(out, x, dlog_bf, c);
        // dX = dlog @ Whead^T  (split-K over V)
        gemm64<<<dim3(D / 64, NTOK / 64, SPLITK), blk256, 0, stream>>>(
            dlog_bf, V, Whead_n, V, Cpart, D, SKLEN, NTOK * D,
            nullptr, nullptr, 0, -1);
        reduce_splitk<<<(NTOK * D) / 256, blk256, 0, stream>>>(Cpart, t512, NTOK * D);
        ln_bwd<<<NTOK, blk256, 0, stream>>>(t512, h[4], lnf_s, nullptr, dh, dh_bf, dhT);
        for (int l = LAYERS - 1; l >= 0; l--) {
            // ---- MLP backward ----
            G(dh_bf, D, W2n + (size_t)l * HID * D, D, du, HID,
              NTOK, HID, D, nullptr, nullptr, 0, -1);
            gemm64_upd<<<dim3(D / 64, HID / 64), blk256, 0, stream>>>(
                uT[l], NTOK, dhT, NTOK, W2m + (size_t)l * HID * D, D, NTOK, LR,
                W2n + (size_t)l * HID * D, W2t + (size_t)l * HID * D, HID);
            colsum_bf<<<(D + 255) / 256, blk256, 0, stream>>>(dh_bf, D, NTOK, b2w + l * D, D, LR);
            gelu_bwd<<<dim3(HID / 64, NTOK / 64), blk256, 0, stream>>>(gbuf[l], du, dg_bf, dgT);
            G(dg_bf, HID, W1n + (size_t)l * D * HID, HID, t512, D,
              NTOK, D, HID, nullptr, nullptr, 0, -1);
            gemm64_upd<<<dim3(HID / 64, D / 64), blk256, 0, stream>>>(
                mbT[l], NTOK, dgT, NTOK, W1m + (size_t)l * D * HID, HID, NTOK, LR,
                W1n + (size_t)l * D * HID, W1t + (size_t)l * D * HID, D);
            colsum_bf<<<(HID + 255) / 256, blk256, 0, stream>>>(dg_bf, HID, NTOK, b1w + l * HID, HID, LR);
            ln_bwd<<<NTOK, blk256, 0, stream>>>(t512, hp[l], ln2_s + l * D, dh, dhp, dhp_bf, nullptr);
            // ---- attention backward ----
            G(dhp_bf, D, Wo_n + (size_t)l * D * D, D, t512, D,
              NTOK, D, D, nullptr, nullptr, 0, -1);
            attn_bwd1<<<16, 128, 0, stream>>>(qkvb[l], attb[l], t512, dS, dqkv_bf);
            attn_bwd2<<<16, 128, 0, stream>>>(qkvb[l], attb[l], dS, t512, dqkv_bf);
            G(dqkv_bf, 1536, Wqkv_n + (size_t)l * D * 1536, 1536, t512, D,
              NTOK, D, 1536, nullptr, nullptr, 0, -1);
            ln_bwd<<<NTOK, blk256, 0, stream>>>(t512, h[l], ln1_s + l * D, dhp, dh, dh_bf, dhT);
        }
    }
}